// Round 8
// baseline (960.400 us; speedup 1.0000x reference)
//
#include <hip/hip_runtime.h>
#include <hip/hip_bf16.h>

#define NROWS 16384
#define DIN   256
#define DH    128
#define SPLITS 4
#define KVSPL  4096              // NROWS / SPLITS
#define KVBLK  64
#define NIT    64                // KVSPL / KVBLK
#define QBLK   256               // q rows per attn block (8 waves x 32)

typedef __attribute__((ext_vector_type(8)))  short  short8;   // 8 bf16 = 16B
typedef __attribute__((ext_vector_type(4)))  float  f32x4;
typedef __attribute__((ext_vector_type(16))) float  f32x16;
typedef __attribute__((ext_vector_type(4)))  unsigned short u16x4;
typedef __attribute__((ext_vector_type(4)))  unsigned int   u32x4;

__device__ __forceinline__ unsigned short f2bf(float f) {
  unsigned int u = __float_as_uint(f);
  unsigned int r = (u + 0x7FFFu + ((u >> 16) & 1u)) >> 16;  // RNE
  return (unsigned short)r;
}
__device__ __forceinline__ float bf2f(unsigned short b) {
  return __uint_as_float(((unsigned int)b) << 16);
}

// async global->LDS, 16B per lane; dst = wave-uniform base + lane*16
__device__ __forceinline__ void gload_lds16(const void* g, void* l) {
  __builtin_amdgcn_global_load_lds(
      (const __attribute__((address_space(1))) unsigned int*)g,
      (__attribute__((address_space(3))) unsigned int*)l, 16, 0, 0);
}

// ---------------------------------------------------------------------------
// Kernel 0: W [256][128] f32 -> W^T [128][256] bf16
// ---------------------------------------------------------------------------
__global__ void prep_w(const float* __restrict__ Wq, const float* __restrict__ Wk,
                       unsigned short* __restrict__ WqT, unsigned short* __restrict__ WkT) {
  const float* W = blockIdx.x ? Wk : Wq;
  unsigned short* WT = blockIdx.x ? WkT : WqT;
  int c = threadIdx.x;  // 0..127
  for (int k = 0; k < DIN; ++k)
    WT[c * DIN + k] = f2bf(W[k * DH + c]);
}

// ---------------------------------------------------------------------------
// Kernel 1: per 64-row H tile (256 blocks x 256 thr):
//   H^T -> HbT bf16; Q = (H@Wq+bq)*SCALE*LOG2E; K = H@Wk+bk (bf16).
//   Q/K stores vectorized via LDS tile bounce.
// ---------------------------------------------------------------------------
__global__ __launch_bounds__(256) void prep_hqk(
    const float* __restrict__ H,
    const unsigned short* __restrict__ WqT, const float* __restrict__ bq,
    const unsigned short* __restrict__ WkT, const float* __restrict__ bk,
    unsigned short* __restrict__ HbT,
    unsigned short* __restrict__ Qb, unsigned short* __restrict__ Kb) {
  __shared__ __align__(16) unsigned short tile[64][264];
  const int tid = threadIdx.x;
  const int qbase = blockIdx.x * 64;

  for (int i = tid; i < 64 * 64; i += 256) {
    int r = i >> 6, c4 = i & 63;
    const f32x4 v = *reinterpret_cast<const f32x4*>(H + (size_t)(qbase + r) * DIN + c4 * 4);
    u16x4 b;
    b[0] = f2bf(v[0]); b[1] = f2bf(v[1]); b[2] = f2bf(v[2]); b[3] = f2bf(v[3]);
    *reinterpret_cast<u16x4*>(&tile[r][c4 * 4]) = b;
  }
  __syncthreads();

  // transposed write HbT[c][qbase..]
  for (int i = tid; i < 256 * 8; i += 256) {
    int c = i >> 3, seg = i & 7;
    short8 t;
#pragma unroll
    for (int j = 0; j < 8; ++j) t[j] = (short)tile[seg * 8 + j][c];
    *reinterpret_cast<short8*>(HbT + (size_t)c * NROWS + qbase + seg * 8) = t;
  }

  const int lane = tid & 63, w = tid >> 6;
  const int col = lane & 15, grp = lane >> 4;

  short8 ah[8];
#pragma unroll
  for (int c = 0; c < 8; ++c)
    ah[c] = *reinterpret_cast<const short8*>(&tile[w * 16 + col][c * 32 + grp * 8]);

  f32x4 accq[8], acck[8];
#pragma unroll
  for (int ct = 0; ct < 8; ++ct) { accq[ct] = f32x4{0,0,0,0}; acck[ct] = f32x4{0,0,0,0}; }

#pragma unroll
  for (int ct = 0; ct < 8; ++ct) {
#pragma unroll
    for (int c = 0; c < 8; ++c) {
      short8 bwq = *reinterpret_cast<const short8*>(WqT + (size_t)(ct * 16 + col) * DIN + c * 32 + grp * 8);
      accq[ct] = __builtin_amdgcn_mfma_f32_16x16x32_bf16(ah[c], bwq, accq[ct], 0, 0, 0);
      short8 bwk = *reinterpret_cast<const short8*>(WkT + (size_t)(ct * 16 + col) * DIN + c * 32 + grp * 8);
      acck[ct] = __builtin_amdgcn_mfma_f32_16x16x32_bf16(ah[c], bwk, acck[ct], 0, 0, 0);
    }
  }

  const float QSCALE = 0.12751742f;  // (1/sqrt(128)) * log2(e)
  float vbq[8], vbk[8];
#pragma unroll
  for (int ct = 0; ct < 8; ++ct) { vbq[ct] = bq[ct * 16 + col]; vbk[ct] = bk[ct * 16 + col]; }

  // ---- Q pass: bounce via tile, vector store ----
  __syncthreads();   // all reads of tile (phase b/c) complete
#pragma unroll
  for (int ct = 0; ct < 8; ++ct)
#pragma unroll
    for (int r = 0; r < 4; ++r)
      tile[w * 16 + grp * 4 + r][ct * 16 + col] = f2bf((accq[ct][r] + vbq[ct]) * QSCALE);
  __syncthreads();
  for (int i = tid; i < 1024; i += 256) {
    int r = i >> 4, seg = i & 15;
    *reinterpret_cast<short8*>(Qb + (size_t)(qbase + r) * DH + seg * 8) =
        *reinterpret_cast<const short8*>(&tile[r][seg * 8]);
  }
  // ---- K pass ----
  __syncthreads();
#pragma unroll
  for (int ct = 0; ct < 8; ++ct)
#pragma unroll
    for (int r = 0; r < 4; ++r)
      tile[w * 16 + grp * 4 + r][ct * 16 + col] = f2bf(acck[ct][r] + vbk[ct]);
  __syncthreads();
  for (int i = tid; i < 1024; i += 256) {
    int r = i >> 4, seg = i & 15;
    *reinterpret_cast<short8*>(Kb + (size_t)(qbase + r) * DH + seg * 8) =
        *reinterpret_cast<const short8*>(&tile[r][seg * 8]);
  }
}

// ---------------------------------------------------------------------------
// Kernel 2: flash attention, m=0 softmax, 4-way kv-split.
// grid 256 = 64 qb x 4 sp. Block = 512 thr = 8 waves x 32 q-rows, full d=256.
// Per iter: [K(t) loads to regs (16 VMEM)] [stage V(t+1) (4 gload_lds)]
// [vmcnt(20) -> V(t) retired] [barrier] [QK^T] [softmax in-reg] [PV].
// V in 4-deep LDS ring (4x32KB), ONE barrier/iter; K direct from L2.
// Swapped QK^T (32x32x16): P lane-local; P->A-frag via cvt_pk + permlane32.
// Raw (unnormalized) bf16 O partials + row-sums out.
// ---------------------------------------------------------------------------
__global__ __launch_bounds__(512, 2) void attn_fa(
    const unsigned short* __restrict__ Qb, const unsigned short* __restrict__ Kb,
    const unsigned short* __restrict__ HbT,
    unsigned short* __restrict__ Opart, float* __restrict__ Lp) {
  __shared__ __align__(16) char lds[131072];   // 4 x 32KB V ring

  const int tid = threadIdx.x;
  const int lane = tid & 63, w = tid >> 6;
  const int l31 = lane & 31, hi = lane >> 5;
  const int vswz = (l31 & 7) << 4;
  const int dlv = l31 - 4 * hi;

  const int sp = blockIdx.x & 3;
  const int qb = blockIdx.x >> 2;
  const int qrow0 = qb * QBLK + w * 32;
  const int kv0 = sp * KVSPL;

  // V staging source constants: wave w covers d = w*32 .. w*32+31.
  // content pre-swizzled by ((d&7)<<4) bytes within each 128B row-chunk.
  size_t voff[4];
#pragma unroll
  for (int s = 0; s < 4; ++s) {
    int d = w * 32 + s * 8 + (lane >> 3);
    voff[s] = (size_t)d * NROWS + (((((lane & 7) * 16) ^ ((lane >> 3) << 4))) >> 1);
  }
  const int vdst = w * 4096;   // + s*1024, wave-uniform

  // Q B-frags (pre-scaled): n = q = l31, k = c*16 + hi*8 + j
  short8 qf[8];
#pragma unroll
  for (int c = 0; c < 8; ++c)
    qf[c] = *reinterpret_cast<const short8*>(Qb + (size_t)(qrow0 + l31) * DH + c * 16 + hi * 8);

  f32x16 acc[8];
#pragma unroll
  for (int dt = 0; dt < 8; ++dt) acc[dt] = {};
  float lsum = 0.f;

  // prologue: stage V(0) into ring slot 0
#pragma unroll
  for (int s = 0; s < 4; ++s)
    gload_lds16(HbT + voff[s] + kv0, lds + vdst + s * 1024);

  for (int ot = 0; ot < NIT / 4; ++ot) {
#pragma unroll
    for (int pz = 0; pz < 4; ++pz) {
      const int it = ot * 4 + pz;
      const int kvbase = kv0 + it * KVBLK;
      const char* Vrd = lds + pz * 32768;
      char* Vwr = lds + ((pz + 1) & 3) * 32768;

      // 1. K(t) frag loads to registers FIRST (16 VMEM, L2-resident)
      const unsigned short* kA = Kb + (size_t)(kvbase + l31) * DH + hi * 8;
      const unsigned short* kB = Kb + (size_t)(kvbase + 32 + l31) * DH + hi * 8;
      short8 ka0[8], ka1[8];
#pragma unroll
      for (int c = 0; c < 8; ++c) {
        ka0[c] = *reinterpret_cast<const short8*>(kA + c * 16);
        ka1[c] = *reinterpret_cast<const short8*>(kB + c * 16);
      }

      // 2. stage V(t+1) into next ring slot (last iter: harmless in-ws OOB)
      {
        const size_t kvn = (size_t)kvbase + KVBLK;
#pragma unroll
        for (int s = 0; s < 4; ++s)
          gload_lds16(HbT + voff[s] + kvn, Vwr + vdst + s * 1024);
      }

      // 3. V(t) retired: outstanding <= stage(t)x4(oldest)+K(t)x16+stage(t+1)x4
      //    vmcnt(20) retires the stage(t) group; K(t)+stage(t+1) stay in flight.
      asm volatile("s_waitcnt vmcnt(20)" ::: "memory");
      __builtin_amdgcn_s_barrier();

      // 4. swapped QK^T: p[kv][q]; A = K regs, B = Q regs
      f32x16 p0 = {}, p1 = {};
      __builtin_amdgcn_s_setprio(1);
#pragma unroll
      for (int c = 0; c < 8; ++c) {
        p0 = __builtin_amdgcn_mfma_f32_32x32x16_bf16(ka0[c], qf[c], p0, 0, 0, 0);
        p1 = __builtin_amdgcn_mfma_f32_32x32x16_bf16(ka1[c], qf[c], p1, 0, 0, 0);
      }
      __builtin_amdgcn_s_setprio(0);

      // 5. diag zero (logit 0 pre-scale -> p=1 after exp2)
      const unsigned dq = (unsigned)(qrow0 - kvbase);
      if (dq < 64u) {
        if (dq == 0) {
#pragma unroll
          for (int r = 0; r < 16; ++r)
            if (dlv == ((r & 3) + 8 * (r >> 2))) p0[r] = 0.f;
        } else {
#pragma unroll
          for (int r = 0; r < 16; ++r)
            if (dlv == ((r & 3) + 8 * (r >> 2))) p1[r] = 0.f;
        }
      }

      // 6. exp2 + lane-local row-sum
#pragma unroll
      for (int r = 0; r < 16; ++r) { p0[r] = exp2f(p0[r]); lsum += p0[r]; }
#pragma unroll
      for (int r = 0; r < 16; ++r) { p1[r] = exp2f(p1[r]); lsum += p1[r]; }

      // 7. P -> bf16 A-frags: 16 cvt_pk + 8 permlane32_swap (dst = low word)
      unsigned int W[16];
#pragma unroll
      for (int j = 0; j < 8; ++j) {
        asm("v_cvt_pk_bf16_f32 %0, %1, %2" : "=v"(W[j])     : "v"(p0[2*j]), "v"(p0[2*j+1]));
        asm("v_cvt_pk_bf16_f32 %0, %1, %2" : "=v"(W[8 + j]) : "v"(p1[2*j]), "v"(p1[2*j+1]));
      }
#pragma unroll
      for (int b = 0; b < 4; ++b) {
        asm("v_permlane32_swap_b32 %0, %1" : "+v"(W[b*4+0]), "+v"(W[b*4+2]));
        asm("v_permlane32_swap_b32 %0, %1" : "+v"(W[b*4+1]), "+v"(W[b*4+3]));
      }

      // 8. PV from LDS ring slot pz
      __builtin_amdgcn_s_setprio(1);
#pragma unroll
      for (int kc = 0; kc < 4; ++kc) {
        u32x4 paw = { W[kc*4+0], W[kc*4+1], W[kc*4+2], W[kc*4+3] };
        short8 pa = __builtin_bit_cast(short8, paw);
        const int off = (kc * 32 + hi * 16) ^ vswz;
#pragma unroll
        for (int dt = 0; dt < 8; ++dt) {
          short8 bv = *reinterpret_cast<const short8*>(Vrd + (dt * 32 + l31) * 128 + off);
          acc[dt] = __builtin_amdgcn_mfma_f32_32x32x16_bf16(pa, bv, acc[dt], 0, 0, 0);
        }
      }
      __builtin_amdgcn_s_setprio(0);
      // no end-of-iter barrier: 4-deep ring, writer targets pz+1, max skew 1
    }
  }

  // ---- epilogue: raw O partials (bf16) + row sums ----
  lsum += __shfl_xor(lsum, 32);   // combine hi/lo k-halves: full l for q=l31

  const size_t obase = (size_t)sp * NROWS * DIN;
#pragma unroll
  for (int dt = 0; dt < 8; ++dt) {
#pragma unroll
    for (int r = 0; r < 16; ++r) {
      int q = qrow0 + (r & 3) + 8 * (r >> 2) + 4 * hi;
      Opart[obase + (size_t)q * DIN + dt * 32 + l31] = f2bf(acc[dt][r]);
    }
  }
  if (lane < 32) Lp[(size_t)sp * NROWS + qrow0 + l31] = lsum;
}

// ---------------------------------------------------------------------------
// Kernel 3: merge 4 raw partials (out = (Sum O_s)/(Sum l_s) + H).
// ---------------------------------------------------------------------------
__global__ __launch_bounds__(256) void merge_split(
    const unsigned short* __restrict__ Opart, const float* __restrict__ Lp,
    const float* __restrict__ H, float* __restrict__ out) {
  const int row = blockIdx.x * 16 + (threadIdx.x >> 4);
  const int d0 = (threadIdx.x & 15) * 16;

  float Wt = 0.f;
#pragma unroll
  for (int s = 0; s < SPLITS; ++s) Wt += Lp[(size_t)s * NROWS + row];
  float invW = 1.0f / Wt;

  float acc[16];
#pragma unroll
  for (int j = 0; j < 16; ++j) acc[j] = 0.f;
#pragma unroll
  for (int s = 0; s < SPLITS; ++s) {
    const unsigned short* p = Opart + ((size_t)s * NROWS + row) * DIN + d0;
#pragma unroll
    for (int h = 0; h < 2; ++h) {
      short8 v = *reinterpret_cast<const short8*>(p + h * 8);
#pragma unroll
      for (int j = 0; j < 8; ++j) acc[h * 8 + j] += bf2f((unsigned short)v[j]);
    }
  }
  const float* hrow = H + (size_t)row * DIN + d0;
  float* orow = out + (size_t)row * DIN + d0;
#pragma unroll
  for (int q = 0; q < 4; ++q) {
    f32x4 hv = *reinterpret_cast<const f32x4*>(hrow + q * 4);
    f32x4 ov;
#pragma unroll
    for (int j = 0; j < 4; ++j) ov[j] = acc[q * 4 + j] * invW + hv[j];
    *reinterpret_cast<f32x4*>(orow + q * 4) = ov;
  }
}

// ---------------------------------------------------------------------------
extern "C" void kernel_launch(void* const* d_in, const int* in_sizes, int n_in,
                              void* d_out, int out_size, void* d_ws, size_t ws_size,
                              hipStream_t stream) {
  const float* H  = (const float*)d_in[0];
  const float* Wq = (const float*)d_in[1];
  const float* bq = (const float*)d_in[2];
  const float* Wk = (const float*)d_in[3];
  const float* bk = (const float*)d_in[4];
  float* out = (float*)d_out;

  char* ws = (char*)d_ws;
  unsigned short* HbT   = (unsigned short*)(ws);                    // 8 MB
  unsigned short* Qb    = (unsigned short*)(ws + 8388608);          // 4 MB
  unsigned short* Kb    = (unsigned short*)(ws + 12582912);         // 4 MB
  unsigned short* WqT   = (unsigned short*)(ws + 16777216);         // 64 KB
  unsigned short* WkT   = (unsigned short*)(ws + 16842752);         // 64 KB
  unsigned short* Opart = (unsigned short*)(ws + 20971520);         // 32 MB
  float*          Lp    = (float*)(ws + 54525952);                  // 256 KB

  prep_w<<<2, 128, 0, stream>>>(Wq, Wk, WqT, WkT);
  prep_hqk<<<256, 256, 0, stream>>>(H, WqT, bq, WkT, bk, HbT, Qb, Kb);
  attn_fa<<<256, 512, 0, stream>>>(Qb, Kb, HbT, Opart, Lp);
  merge_split<<<1024, 256, 0, stream>>>(Opart, Lp, H, out);
}